// Round 9
// baseline (218.559 us; speedup 1.0000x reference)
//
#include <hip/hip_runtime.h>

#define S_LEN   2048
#define D_MODEL 1024
#define N_HEADS 16
#define HEAD_DIM 64

typedef unsigned short u16;
typedef float  floatx4 __attribute__((ext_vector_type(4)));
typedef short  bf16x8  __attribute__((ext_vector_type(8)));
typedef short  bf16x4  __attribute__((ext_vector_type(4)));

__device__ __forceinline__ u16 f2bf(float f) {
    unsigned int u = __float_as_uint(f);
    u += 0x7FFF + ((u >> 16) & 1);      // RNE
    return (u16)(u >> 16);
}
__device__ __forceinline__ unsigned pack2bf(float a, float b) {
    return (unsigned)f2bf(a) | ((unsigned)f2bf(b) << 16);
}

// global -> LDS direct copy, 16B/lane. LDS dest = wave-uniform base + lane*16.
__device__ __forceinline__ void gload_lds16(const void* g, void* l) {
    __builtin_amdgcn_global_load_lds(
        reinterpret_cast<const __attribute__((address_space(1))) unsigned int*>(
            reinterpret_cast<uintptr_t>(g)),
        reinterpret_cast<__attribute__((address_space(3))) unsigned int*>(
            reinterpret_cast<uintptr_t>(l)),
        16, 0, 0);
}

// ---------------------------------------------------------------------------
// Single fused fp32 -> bf16 cast for hs + 4 weights (dst regions contiguous).
// ---------------------------------------------------------------------------
__global__ __launch_bounds__(256) void cast_all(const float* __restrict__ hs,
                                                const float* __restrict__ w0,
                                                const float* __restrict__ w1,
                                                const float* __restrict__ w2,
                                                const float* __restrict__ w3,
                                                u16* __restrict__ dst) {
    const size_t NHS = (size_t)2 * S_LEN * D_MODEL;   // 4M
    const size_t e0 = (size_t)blockIdx.x * 2048;      // block-uniform range
    const float* src;
    size_t base;
    if (e0 < NHS)                 { src = hs; base = 0; }
    else {
        const int wi = (int)((e0 - NHS) >> 20);       // 1M-element weights
        src = wi == 0 ? w0 : wi == 1 ? w1 : wi == 2 ? w2 : w3;
        base = NHS + ((size_t)wi << 20);
    }
    const size_t i = e0 + (size_t)threadIdx.x * 8;
    const float4 a = *(const float4*)(src + (i - base));
    const float4 b = *(const float4*)(src + (i - base) + 4);
    uint4 o;
    o.x = pack2bf(a.x, a.y); o.y = pack2bf(a.z, a.w);
    o.z = pack2bf(b.x, b.y); o.w = pack2bf(b.z, b.w);
    *(uint4*)(dst + i) = o;
}

// ---------------------------------------------------------------------------
// Per-head V transpose (head (b,h) is a CONTIGUOUS (2048 s, 64 d) slab under
// the module's direct reshape view). Vt[bh][d][s]. Coalesced both sides.
// ---------------------------------------------------------------------------
__global__ __launch_bounds__(256) void vtrans(const u16* __restrict__ Vf,
                                              u16* __restrict__ Vt) {
    __shared__ unsigned T[64 * 133];
    const int bh = blockIdx.y;            // 0..31
    const int sBase = blockIdx.x * 128;
    const u16* src = Vf + (size_t)bh * (S_LEN * HEAD_DIM) + (size_t)sBase * HEAD_DIM;
    u16* dst = Vt + (size_t)bh * (S_LEN * HEAD_DIM) + sBase;
    const int tid = threadIdx.x;

#pragma unroll
    for (int it = 0; it < 4; ++it) {
        const int idx = it * 256 + tid;
        const int row = idx >> 3, ch = idx & 7;
        const float4 v4 = *(const float4*)(src + row * 64 + ch * 8);
        const u16* vs = (const u16*)&v4;
#pragma unroll
        for (int j = 0; j < 8; ++j) T[(ch * 8 + j) * 133 + row] = vs[j];
    }
    __syncthreads();
#pragma unroll
    for (int it = 0; it < 4; ++it) {
        const int idx = it * 256 + tid;
        const int d = idx >> 4, sc = idx & 15;
        union { u16 u[8]; float4 f; } tmp;
#pragma unroll
        for (int j = 0; j < 8; ++j) tmp.u[j] = (u16)T[d * 133 + sc * 8 + j];
        *(float4*)(dst + (size_t)d * S_LEN + sc * 8) = tmp.f;
    }
}

// ---------------------------------------------------------------------------
// Fused QKV GEMM, 128x128 tile, BK=64. LDS rows 64 u16 = 128 B with the
// slot^(row&7) XOR swizzle. 1D grid 768, XCD-by-m-tile mapping.
// Q pre-scaled by log2e/64.
// ---------------------------------------------------------------------------
__global__ __launch_bounds__(256, 3) void gemm_qkv(const u16* __restrict__ A,
                                                   const u16* __restrict__ Wq,
                                                   const u16* __restrict__ Wk,
                                                   const u16* __restrict__ Wv,
                                                   u16* __restrict__ Qo,
                                                   u16* __restrict__ Ko,
                                                   u16* __restrict__ Vfo) {
    __shared__ u16 As[128 * 64];          // 16 KB
    __shared__ u16 Ws[128 * 64];          // 16 KB

    const int blk = blockIdx.x;                            // 0..767
    const int y   = (blk & 7) | (((blk >> 3) & 3) << 3);   // m-tile, XCD = y%8
    const int x   = blk >> 5;                              // 0..23
    const int which = x >> 3;
    const int nBase = (x & 7) * 128;
    const int mBase = y * 128;
    const u16* W = which == 0 ? Wq : which == 1 ? Wk : Wv;

    const int tid = threadIdx.x, lane = tid & 63, wv = tid >> 6;
    const int l15 = lane & 15, quad = lane >> 4;
    const int wm = wv & 1, wn = wv >> 1;
    const int srow = lane >> 3;           // 0..7 (row within 8-row chunk)
    const int gch  = (lane & 7) ^ srow;   // swizzled source chunk (8 B units)
    const int swz  = l15 & 7;             // read-side swizzle (row&7 == l15&7)

    floatx4 acc[4][4];
#pragma unroll
    for (int i = 0; i < 4; ++i)
#pragma unroll
        for (int j = 0; j < 4; ++j) acc[i][j] = (floatx4)(0.0f);

    for (int k0 = 0; k0 < D_MODEL; k0 += 64) {
        __syncthreads();
#pragma unroll
        for (int t = 0; t < 4; ++t) {
            const int ci = wv * 4 + t;    // 16 chunks of 8 rows x 64 cols
            gload_lds16(A + (size_t)(mBase + ci * 8 + srow) * D_MODEL + k0 + gch * 8,
                        &As[ci * 512]);
            gload_lds16(W + (size_t)(nBase + ci * 8 + srow) * D_MODEL + k0 + gch * 8,
                        &Ws[ci * 512]);
        }
        __syncthreads();

#pragma unroll
        for (int ks = 0; ks < 2; ++ks) {
            bf16x8 af[4], bfr[4];
#pragma unroll
            for (int mt = 0; mt < 4; ++mt)
                af[mt] = *(const bf16x8*)&As[(wm * 64 + mt * 16 + l15) * 64
                                             + ((ks * 4 + quad) ^ swz) * 8];
#pragma unroll
            for (int nt = 0; nt < 4; ++nt)
                bfr[nt] = *(const bf16x8*)&Ws[(wn * 64 + nt * 16 + l15) * 64
                                              + ((ks * 4 + quad) ^ swz) * 8];
#pragma unroll
            for (int mt = 0; mt < 4; ++mt)
#pragma unroll
                for (int nt = 0; nt < 4; ++nt)
                    acc[mt][nt] = __builtin_amdgcn_mfma_f32_16x16x32_bf16(af[mt], bfr[nt], acc[mt][nt], 0, 0, 0);
        }
    }

    u16* O = which == 0 ? Qo : (which == 1 ? Ko : Vfo);
    const float scale = which == 0 ? (1.44269504088896f / 64.0f) : 1.0f;
#pragma unroll
    for (int mt = 0; mt < 4; ++mt)
#pragma unroll
        for (int nt = 0; nt < 4; ++nt) {
            const int col = nBase + wn * 64 + nt * 16 + l15;
#pragma unroll
            for (int r = 0; r < 4; ++r) {
                const int row = mBase + wm * 64 + mt * 16 + quad * 4 + r;
                O[(size_t)row * D_MODEL + col] = f2bf(acc[mt][nt][r] * scale);
            }
        }
}

// ---------------------------------------------------------------------------
// O-projection GEMM: 64x128 tile (512 blocks -> 2/CU), BK=64, fp32 out + bias.
// ---------------------------------------------------------------------------
__global__ __launch_bounds__(256, 3) void gemm_out(const u16* __restrict__ A,
                                                   const u16* __restrict__ W,
                                                   const float* __restrict__ bias,
                                                   float* __restrict__ C) {
    __shared__ u16 As[64 * 64];           // 8 KB
    __shared__ u16 Ws[128 * 64];          // 16 KB

    const int nBase = blockIdx.x * 128;
    const int mBase = blockIdx.y * 64;
    const int tid = threadIdx.x, lane = tid & 63, wv = tid >> 6;
    const int l15 = lane & 15, quad = lane >> 4;
    const int wm = wv & 1, wn = wv >> 1;
    const int srow = lane >> 3;
    const int gch  = (lane & 7) ^ srow;
    const int swz  = l15 & 7;

    floatx4 acc[2][4];
#pragma unroll
    for (int i = 0; i < 2; ++i)
#pragma unroll
        for (int j = 0; j < 4; ++j) acc[i][j] = (floatx4)(0.0f);

    for (int k0 = 0; k0 < D_MODEL; k0 += 64) {
        __syncthreads();
#pragma unroll
        for (int t = 0; t < 2; ++t) {
            const int ci = wv * 2 + t;    // 8 chunks: rows 0..63
            gload_lds16(A + (size_t)(mBase + ci * 8 + srow) * D_MODEL + k0 + gch * 8,
                        &As[ci * 512]);
        }
#pragma unroll
        for (int t = 0; t < 4; ++t) {
            const int ci = wv * 4 + t;    // 16 chunks: rows 0..127
            gload_lds16(W + (size_t)(nBase + ci * 8 + srow) * D_MODEL + k0 + gch * 8,
                        &Ws[ci * 512]);
        }
        __syncthreads();

#pragma unroll
        for (int ks = 0; ks < 2; ++ks) {
            bf16x8 af[2], bfr[4];
#pragma unroll
            for (int mt = 0; mt < 2; ++mt)
                af[mt] = *(const bf16x8*)&As[(wm * 32 + mt * 16 + l15) * 64
                                             + ((ks * 4 + quad) ^ swz) * 8];
#pragma unroll
            for (int nt = 0; nt < 4; ++nt)
                bfr[nt] = *(const bf16x8*)&Ws[(wn * 64 + nt * 16 + l15) * 64
                                              + ((ks * 4 + quad) ^ swz) * 8];
#pragma unroll
            for (int mt = 0; mt < 2; ++mt)
#pragma unroll
                for (int nt = 0; nt < 4; ++nt)
                    acc[mt][nt] = __builtin_amdgcn_mfma_f32_16x16x32_bf16(af[mt], bfr[nt], acc[mt][nt], 0, 0, 0);
        }
    }

#pragma unroll
    for (int mt = 0; mt < 2; ++mt)
#pragma unroll
        for (int nt = 0; nt < 4; ++nt) {
            const int col = nBase + wn * 64 + nt * 16 + l15;
            const float bv = bias[col];
#pragma unroll
            for (int r = 0; r < 4; ++r) {
                const int row = mBase + wm * 32 + mt * 16 + quad * 4 + r;
                C[(size_t)row * D_MODEL + col] = acc[mt][nt][r] + bv;
            }
        }
}

// ---------------------------------------------------------------------------
// MFMA flash attention v10: QBLK=128 via 8-wave blocks (512 thr, 512 blocks).
// Waves 0-3 own q-subtile 0, waves 4-7 own q-subtile 1 (qh = wv>>2); within a
// group, wave kw = wv&3 owns keys [kw*16, kw*16+16) — the per-wave inner loop
// is IDENTICAL to the verified R6 code (kw substituted for wv). One staged
// K/V tile now serves 128 queries: staged tiles 16896 -> 8704 (-48%),
// barriers halved, 16 waves/CU (2 blocks x 8). Block->qp mapping pairs
// long+short blocks so each CU's 2 resident blocks sum to 36 tiles.
// qh=0 waves idle (barrier-only) during the block's final tile.
// Reduction: two independent 4-wave trees (one per qh), buffers alias the
// 32 KB stage region. LDS 70 KB -> 2 blocks/CU.
// ---------------------------------------------------------------------------
__global__ __launch_bounds__(512, 4) void attn8(const u16* __restrict__ Q,
                                                const u16* __restrict__ K,
                                                const u16* __restrict__ Vt,
                                                u16* __restrict__ Ctx) {
    __shared__ __align__(16) char smem[71680];
    u16*   Ks    = (u16*)smem;                 // [2][4096] K tiles (swizzled)
    u16*   Vs    = (u16*)(smem + 16384);       // [2][4096] V tiles (swizzled)
    float* lpbuf = (float*)(smem + 69632);     // [2][4][64]

    const int flat = blockIdx.x;          // 0..511
    const int g    = flat & 31;           // (b*16+h); XCD = g%8
    const int jj   = flat >> 5;           // 0..15
    const int qp   = (jj < 8) ? (15 - jj) : (jj - 8);   // paired long+short
    const int h = g & 15, b = g >> 4;

    const int tid = threadIdx.x, lane = tid & 63, wv = tid >> 6;  // wv 0..7
    const int kw = wv & 3, qh = wv >> 2;
    const int l15 = lane & 15, quad = lane >> 4;

    float* R0 = (float*)(smem + qh * 34816);            // aliases stage region
    float* R1 = (float*)(smem + qh * 34816 + 17408);

    const size_t headOff = ((size_t)b * N_HEADS + h) * S_LEN * HEAD_DIM;
    const u16* Qh = Q + headOff;
    const u16* Kh = K + headOff;
    const u16* Vh = Vt + headOff;         // d-major: [64][2048]
    u16* Cb = Ctx + (size_t)b * S_LEN * D_MODEL + (size_t)h * HEAD_DIM;

    const int srow = lane >> 3;           // staging: row within 8-row chunk
    const int gch  = (lane & 7) ^ srow;   // swizzled source chunk
    const int swz  = l15 & 7;             // read-side swizzle (row&7 == l15&7)

    const int qBase = (qp * 2 + qh) * 64;
    const int qtw   = qp * 2 + qh;        // this wave-group's causal limit
    const int qtmax = qp * 2 + 1;         // block's last staged tile

    bf16x8 qb[4][2];
#pragma unroll
    for (int qg = 0; qg < 4; ++qg)
#pragma unroll
        for (int ks = 0; ks < 2; ++ks)
            qb[qg][ks] = *(const bf16x8*)(Qh + (size_t)(qBase + qg * 16 + l15) * 64
                                          + ks * 32 + quad * 8);

    floatx4 o[4][4];                      // O_partial[qg][dg], lane: q=quad*4+r, d=l15
#pragma unroll
    for (int qg = 0; qg < 4; ++qg)
#pragma unroll
        for (int dg = 0; dg < 4; ++dg) o[qg][dg] = (floatx4)(0.0f);
    float lp[4] = {0.0f, 0.0f, 0.0f, 0.0f};

    // prologue: stage tile 0 (each wave: 1 K chunk + 1 V chunk)
    gload_lds16(Kh + (size_t)(wv * 8 + srow) * 64 + gch * 8, &Ks[wv * 512]);
    gload_lds16(Vh + (size_t)(wv * 8 + srow) * S_LEN + gch * 8, &Vs[wv * 512]);
    __syncthreads();                      // buf0 ready

    for (int kt = 0; kt <= qtmax; ++kt) {
        const int cur = (kt & 1) * 4096;
        const int nxt = 4096 - cur;

        if (kt < qtmax) {                 // stage next tile FIRST
            const int kB2 = (kt + 1) * 64;
            gload_lds16(Kh + (size_t)(kB2 + wv * 8 + srow) * 64 + gch * 8,
                        &Ks[nxt + wv * 512]);
            gload_lds16(Vh + (size_t)(wv * 8 + srow) * S_LEN + kB2 + gch * 8,
                        &Vs[nxt + wv * 512]);
        }

        if (kt <= qtw) {                  // qh=0 waves skip the final tile
            bf16x8 ka[2];
#pragma unroll
            for (int ks = 0; ks < 2; ++ks)
                ka[ks] = *(const bf16x8*)&Ks[cur + (kw * 16 + l15) * 64
                                             + ((ks * 4 + quad) ^ swz) * 8];

            bf16x4 vb[4];
#pragma unroll
            for (int dg = 0; dg < 4; ++dg)
                vb[dg] = *(const bf16x4*)&Vs[cur + (dg * 16 + l15) * 64
                                             + (((kw * 2 + (quad >> 1)) ^ swz) * 8) + (quad & 1) * 4];

            floatx4 s[4];
#pragma unroll
            for (int qg = 0; qg < 4; ++qg) {
                s[qg] = (floatx4)(0.0f);
#pragma unroll
                for (int ks = 0; ks < 2; ++ks)
                    s[qg] = __builtin_amdgcn_mfma_f32_16x16x32_bf16(ka[ks], qb[qg][ks], s[qg], 0, 0, 0);
            }

            const bool diag = (kt == qtw);
#pragma unroll
            for (int qg = 0; qg < 4; ++qg) {
                if (diag && qg < kw) continue;      // fully masked (wave-uniform)
                float p[4];
#pragma unroll
                for (int r = 0; r < 4; ++r) {
                    float pv = __builtin_amdgcn_exp2f(s[qg][r]);
                    if (diag && qg == kw && (quad * 4 + r > l15)) pv = 0.0f;
                    p[r] = pv;
                    lp[qg] += pv;
                }
                union { uint2 u; bf16x4 v; } pk;
                pk.u.x = __builtin_amdgcn_perm(__float_as_uint(p[1]), __float_as_uint(p[0]), 0x07060302);
                pk.u.y = __builtin_amdgcn_perm(__float_as_uint(p[3]), __float_as_uint(p[2]), 0x07060302);
#pragma unroll
                for (int dg = 0; dg < 4; ++dg)
                    o[qg][dg] = __builtin_amdgcn_mfma_f32_16x16x16bf16_1k(pk.v, vb[dg], o[qg][dg], 0, 0, 0);
            }
        }

        __syncthreads();   // ONE barrier/tile: drains stage + readers done
    }

    // lp: sum each wave's 16-key slice across quads -> lpbuf[qh][kw][q]
#pragma unroll
    for (int qg = 0; qg < 4; ++qg) {
        lp[qg] += __shfl_xor(lp[qg], 16);
        lp[qg] += __shfl_xor(lp[qg], 32);
    }
    lpbuf[qh * 256 + kw * 64 + quad * 16 + l15] = lp[quad];

    // O tree reduction within each qh group (Red[d][q], pad 68)
    if (kw == 1 || kw == 3) {
        float* R = (kw == 1) ? R0 : R1;
#pragma unroll
        for (int qg = 0; qg < 4; ++qg)
#pragma unroll
            for (int dg = 0; dg < 4; ++dg)
                *(floatx4*)&R[(dg * 16 + l15) * 68 + qg * 16 + quad * 4] = o[qg][dg];
    }
    __syncthreads();
    if (kw == 0 || kw == 2) {
        const float* R = (kw == 0) ? R0 : R1;
#pragma unroll
        for (int qg = 0; qg < 4; ++qg)
#pragma unroll
            for (int dg = 0; dg < 4; ++dg)
                o[qg][dg] += *(const floatx4*)&R[(dg * 16 + l15) * 68 + qg * 16 + quad * 4];
    }
    __syncthreads();
    if (kw == 2) {
#pragma unroll
        for (int qg = 0; qg < 4; ++qg)
#pragma unroll
            for (int dg = 0; dg < 4; ++dg)
                *(floatx4*)&R0[(dg * 16 + l15) * 68 + qg * 16 + quad * 4] = o[qg][dg];
    }
    __syncthreads();
    if (kw == 0) {
#pragma unroll
        for (int qg = 0; qg < 4; ++qg) {
#pragma unroll
            for (int dg = 0; dg < 4; ++dg)
                o[qg][dg] += *(const floatx4*)&R0[(dg * 16 + l15) * 68 + qg * 16 + quad * 4];
            floatx4 lt = *(const floatx4*)&lpbuf[qh * 256 + 0 * 64 + qg * 16 + quad * 4];
            lt += *(const floatx4*)&lpbuf[qh * 256 + 1 * 64 + qg * 16 + quad * 4];
            lt += *(const floatx4*)&lpbuf[qh * 256 + 2 * 64 + qg * 16 + quad * 4];
            lt += *(const floatx4*)&lpbuf[qh * 256 + 3 * 64 + qg * 16 + quad * 4];
#pragma unroll
            for (int r = 0; r < 4; ++r) {
                const float inv = 1.0f / lt[r];
                const int row = qBase + qg * 16 + quad * 4 + r;
#pragma unroll
                for (int dg = 0; dg < 4; ++dg)
                    Cb[(size_t)row * D_MODEL + dg * 16 + l15] = f2bf(o[qg][dg][r] * inv);
            }
        }
    }
}

// ---------------------------------------------------------------------------
extern "C" void kernel_launch(void* const* d_in, const int* in_sizes, int n_in,
                              void* d_out, int out_size, void* d_ws, size_t ws_size,
                              hipStream_t stream) {
    const float* hs = (const float*)d_in[0];
    const float* Wq = (const float*)d_in[1];
    const float* Wk = (const float*)d_in[2];
    const float* Wv = (const float*)d_in[3];
    const float* Wo = (const float*)d_in[4];
    const float* bo = (const float*)d_in[5];
    float* out = (float*)d_out;

    const size_t NHS = (size_t)2 * S_LEN * D_MODEL;  // 4M elements
    const size_t NW  = (size_t)D_MODEL * D_MODEL;    // 1M elements

    u16* hsb = (u16*)d_ws;        // 4M
    u16* Wb  = hsb + NHS;         // 4 x 1M (Wq,Wk,Wv,Wo) — contiguous with hsb
    u16* Qb  = Wb + 4 * NW;       // 4M
    u16* Kb  = Qb + NHS;          // 4M
    u16* Vfb = Kb + NHS;          // 4M (standard projection layout)
    u16* Vtb = Vfb + NHS;         // 4M (per-head transposed [d][s])
    u16* Cxb = Vtb + NHS;         // 4M

    cast_all<<<4096, 256, 0, stream>>>(hs, Wq, Wk, Wv, Wo, hsb);

    gemm_qkv<<<768, 256, 0, stream>>>(hsb, Wb, Wb + NW, Wb + 2 * NW,
                                      Qb, Kb, Vfb);

    vtrans<<<dim3(16, 32), 256, 0, stream>>>(Vfb, Vtb);

    attn8<<<512, 512, 0, stream>>>(Qb, Kb, Vtb, Cxb);

    gemm_out<<<dim3(8, 64), 256, 0, stream>>>(Cxb, Wb + 3 * NW, bo, out);
}

// Round 10
// 164.663 us; speedup vs baseline: 1.3273x; 1.3273x over previous
//
#include <hip/hip_runtime.h>

#define S_LEN   2048
#define D_MODEL 1024
#define N_HEADS 16
#define HEAD_DIM 64

typedef unsigned short u16;
typedef float  floatx4 __attribute__((ext_vector_type(4)));
typedef short  bf16x8  __attribute__((ext_vector_type(8)));
typedef short  bf16x4  __attribute__((ext_vector_type(4)));

__device__ __forceinline__ u16 f2bf(float f) {
    unsigned int u = __float_as_uint(f);
    u += 0x7FFF + ((u >> 16) & 1);      // RNE
    return (u16)(u >> 16);
}
__device__ __forceinline__ unsigned pack2bf(float a, float b) {
    return (unsigned)f2bf(a) | ((unsigned)f2bf(b) << 16);
}

// global -> LDS direct copy, 16B/lane. LDS dest = wave-uniform base + lane*16.
__device__ __forceinline__ void gload_lds16(const void* g, void* l) {
    __builtin_amdgcn_global_load_lds(
        reinterpret_cast<const __attribute__((address_space(1))) unsigned int*>(
            reinterpret_cast<uintptr_t>(g)),
        reinterpret_cast<__attribute__((address_space(3))) unsigned int*>(
            reinterpret_cast<uintptr_t>(l)),
        16, 0, 0);
}

// ---------------------------------------------------------------------------
// Single fused fp32 -> bf16 cast for hs + 4 weights (dst regions contiguous).
// ---------------------------------------------------------------------------
__global__ __launch_bounds__(256) void cast_all(const float* __restrict__ hs,
                                                const float* __restrict__ w0,
                                                const float* __restrict__ w1,
                                                const float* __restrict__ w2,
                                                const float* __restrict__ w3,
                                                u16* __restrict__ dst) {
    const size_t NHS = (size_t)2 * S_LEN * D_MODEL;   // 4M
    const size_t e0 = (size_t)blockIdx.x * 2048;      // block-uniform range
    const float* src;
    size_t base;
    if (e0 < NHS)                 { src = hs; base = 0; }
    else {
        const int wi = (int)((e0 - NHS) >> 20);       // 1M-element weights
        src = wi == 0 ? w0 : wi == 1 ? w1 : wi == 2 ? w2 : w3;
        base = NHS + ((size_t)wi << 20);
    }
    const size_t i = e0 + (size_t)threadIdx.x * 8;
    const float4 a = *(const float4*)(src + (i - base));
    const float4 b = *(const float4*)(src + (i - base) + 4);
    uint4 o;
    o.x = pack2bf(a.x, a.y); o.y = pack2bf(a.z, a.w);
    o.z = pack2bf(b.x, b.y); o.w = pack2bf(b.z, b.w);
    *(uint4*)(dst + i) = o;
}

// ---------------------------------------------------------------------------
// Per-head V transpose (head (b,h) is a CONTIGUOUS (2048 s, 64 d) slab under
// the module's direct reshape view). Vt[bh][d][s]. Coalesced both sides.
// ---------------------------------------------------------------------------
__global__ __launch_bounds__(256) void vtrans(const u16* __restrict__ Vf,
                                              u16* __restrict__ Vt) {
    __shared__ unsigned T[64 * 133];
    const int bh = blockIdx.y;            // 0..31
    const int sBase = blockIdx.x * 128;
    const u16* src = Vf + (size_t)bh * (S_LEN * HEAD_DIM) + (size_t)sBase * HEAD_DIM;
    u16* dst = Vt + (size_t)bh * (S_LEN * HEAD_DIM) + sBase;
    const int tid = threadIdx.x;

#pragma unroll
    for (int it = 0; it < 4; ++it) {
        const int idx = it * 256 + tid;
        const int row = idx >> 3, ch = idx & 7;
        const float4 v4 = *(const float4*)(src + row * 64 + ch * 8);
        const u16* vs = (const u16*)&v4;
#pragma unroll
        for (int j = 0; j < 8; ++j) T[(ch * 8 + j) * 133 + row] = vs[j];
    }
    __syncthreads();
#pragma unroll
    for (int it = 0; it < 4; ++it) {
        const int idx = it * 256 + tid;
        const int d = idx >> 4, sc = idx & 15;
        union { u16 u[8]; float4 f; } tmp;
#pragma unroll
        for (int j = 0; j < 8; ++j) tmp.u[j] = (u16)T[d * 133 + sc * 8 + j];
        *(float4*)(dst + (size_t)d * S_LEN + sc * 8) = tmp.f;
    }
}

// ---------------------------------------------------------------------------
// Fused QKV GEMM, 128x128 tile, BK=64. LDS rows 64 u16 = 128 B with the
// slot^(row&7) XOR swizzle. 1D grid 768, XCD-by-m-tile mapping.
// Q pre-scaled by log2e/64.
// ---------------------------------------------------------------------------
__global__ __launch_bounds__(256, 3) void gemm_qkv(const u16* __restrict__ A,
                                                   const u16* __restrict__ Wq,
                                                   const u16* __restrict__ Wk,
                                                   const u16* __restrict__ Wv,
                                                   u16* __restrict__ Qo,
                                                   u16* __restrict__ Ko,
                                                   u16* __restrict__ Vfo) {
    __shared__ u16 As[128 * 64];          // 16 KB
    __shared__ u16 Ws[128 * 64];          // 16 KB

    const int blk = blockIdx.x;                            // 0..767
    const int y   = (blk & 7) | (((blk >> 3) & 3) << 3);   // m-tile, XCD = y%8
    const int x   = blk >> 5;                              // 0..23
    const int which = x >> 3;
    const int nBase = (x & 7) * 128;
    const int mBase = y * 128;
    const u16* W = which == 0 ? Wq : which == 1 ? Wk : Wv;

    const int tid = threadIdx.x, lane = tid & 63, wv = tid >> 6;
    const int l15 = lane & 15, quad = lane >> 4;
    const int wm = wv & 1, wn = wv >> 1;
    const int srow = lane >> 3;           // 0..7 (row within 8-row chunk)
    const int gch  = (lane & 7) ^ srow;   // swizzled source chunk (8 B units)
    const int swz  = l15 & 7;             // read-side swizzle (row&7 == l15&7)

    floatx4 acc[4][4];
#pragma unroll
    for (int i = 0; i < 4; ++i)
#pragma unroll
        for (int j = 0; j < 4; ++j) acc[i][j] = (floatx4)(0.0f);

    for (int k0 = 0; k0 < D_MODEL; k0 += 64) {
        __syncthreads();
#pragma unroll
        for (int t = 0; t < 4; ++t) {
            const int ci = wv * 4 + t;    // 16 chunks of 8 rows x 64 cols
            gload_lds16(A + (size_t)(mBase + ci * 8 + srow) * D_MODEL + k0 + gch * 8,
                        &As[ci * 512]);
            gload_lds16(W + (size_t)(nBase + ci * 8 + srow) * D_MODEL + k0 + gch * 8,
                        &Ws[ci * 512]);
        }
        __syncthreads();

#pragma unroll
        for (int ks = 0; ks < 2; ++ks) {
            bf16x8 af[4], bfr[4];
#pragma unroll
            for (int mt = 0; mt < 4; ++mt)
                af[mt] = *(const bf16x8*)&As[(wm * 64 + mt * 16 + l15) * 64
                                             + ((ks * 4 + quad) ^ swz) * 8];
#pragma unroll
            for (int nt = 0; nt < 4; ++nt)
                bfr[nt] = *(const bf16x8*)&Ws[(wn * 64 + nt * 16 + l15) * 64
                                              + ((ks * 4 + quad) ^ swz) * 8];
#pragma unroll
            for (int mt = 0; mt < 4; ++mt)
#pragma unroll
                for (int nt = 0; nt < 4; ++nt)
                    acc[mt][nt] = __builtin_amdgcn_mfma_f32_16x16x32_bf16(af[mt], bfr[nt], acc[mt][nt], 0, 0, 0);
        }
    }

    u16* O = which == 0 ? Qo : (which == 1 ? Ko : Vfo);
    const float scale = which == 0 ? (1.44269504088896f / 64.0f) : 1.0f;
#pragma unroll
    for (int mt = 0; mt < 4; ++mt)
#pragma unroll
        for (int nt = 0; nt < 4; ++nt) {
            const int col = nBase + wn * 64 + nt * 16 + l15;
#pragma unroll
            for (int r = 0; r < 4; ++r) {
                const int row = mBase + wm * 64 + mt * 16 + quad * 4 + r;
                O[(size_t)row * D_MODEL + col] = f2bf(acc[mt][nt][r] * scale);
            }
        }
}

// ---------------------------------------------------------------------------
// O-projection GEMM: 64x128 tile (512 blocks -> 2/CU), BK=64, fp32 out + bias.
// ---------------------------------------------------------------------------
__global__ __launch_bounds__(256, 3) void gemm_out(const u16* __restrict__ A,
                                                   const u16* __restrict__ W,
                                                   const float* __restrict__ bias,
                                                   float* __restrict__ C) {
    __shared__ u16 As[64 * 64];           // 8 KB
    __shared__ u16 Ws[128 * 64];          // 16 KB

    const int nBase = blockIdx.x * 128;
    const int mBase = blockIdx.y * 64;
    const int tid = threadIdx.x, lane = tid & 63, wv = tid >> 6;
    const int l15 = lane & 15, quad = lane >> 4;
    const int wm = wv & 1, wn = wv >> 1;
    const int srow = lane >> 3;
    const int gch  = (lane & 7) ^ srow;
    const int swz  = l15 & 7;

    floatx4 acc[2][4];
#pragma unroll
    for (int i = 0; i < 2; ++i)
#pragma unroll
        for (int j = 0; j < 4; ++j) acc[i][j] = (floatx4)(0.0f);

    for (int k0 = 0; k0 < D_MODEL; k0 += 64) {
        __syncthreads();
#pragma unroll
        for (int t = 0; t < 2; ++t) {
            const int ci = wv * 2 + t;    // 8 chunks: rows 0..63
            gload_lds16(A + (size_t)(mBase + ci * 8 + srow) * D_MODEL + k0 + gch * 8,
                        &As[ci * 512]);
        }
#pragma unroll
        for (int t = 0; t < 4; ++t) {
            const int ci = wv * 4 + t;    // 16 chunks: rows 0..127
            gload_lds16(W + (size_t)(nBase + ci * 8 + srow) * D_MODEL + k0 + gch * 8,
                        &Ws[ci * 512]);
        }
        __syncthreads();

#pragma unroll
        for (int ks = 0; ks < 2; ++ks) {
            bf16x8 af[2], bfr[4];
#pragma unroll
            for (int mt = 0; mt < 2; ++mt)
                af[mt] = *(const bf16x8*)&As[(wm * 32 + mt * 16 + l15) * 64
                                             + ((ks * 4 + quad) ^ swz) * 8];
#pragma unroll
            for (int nt = 0; nt < 4; ++nt)
                bfr[nt] = *(const bf16x8*)&Ws[(wn * 64 + nt * 16 + l15) * 64
                                              + ((ks * 4 + quad) ^ swz) * 8];
#pragma unroll
            for (int mt = 0; mt < 2; ++mt)
#pragma unroll
                for (int nt = 0; nt < 4; ++nt)
                    acc[mt][nt] = __builtin_amdgcn_mfma_f32_16x16x32_bf16(af[mt], bfr[nt], acc[mt][nt], 0, 0, 0);
        }
    }

#pragma unroll
    for (int mt = 0; mt < 2; ++mt)
#pragma unroll
        for (int nt = 0; nt < 4; ++nt) {
            const int col = nBase + wn * 64 + nt * 16 + l15;
            const float bv = bias[col];
#pragma unroll
            for (int r = 0; r < 4; ++r) {
                const int row = mBase + wm * 32 + mt * 16 + quad * 4 + r;
                C[(size_t)row * D_MODEL + col] = acc[mt][nt][r] + bv;
            }
        }
}

// ---------------------------------------------------------------------------
// MFMA flash attention v7 (round-6 verified structure, 165.1 µs state) +
// T5 s_setprio around the MFMA/softmax cluster (single change this round;
// m191 isolated +4-7% on attn). Key-split across 4 waves, QBLK=64, 1024
// blocks longest-first XCD-pinned, single __syncthreads per tile with
// early next-tile stage. Reduction buffers alias the stage region.
// LDS 35 KB -> 3 blocks/CU.
// [R9 lesson: QBLK=128 8-wave = -53 µs (dispatch-order load balance invalid,
//  2 blocks/CU TLP insufficient). R8: counted vmcnt = neutral at 3 blk/CU.]
// ---------------------------------------------------------------------------
__global__ __launch_bounds__(256, 3) void attn6(const u16* __restrict__ Q,
                                                const u16* __restrict__ K,
                                                const u16* __restrict__ Vt,
                                                u16* __restrict__ Ctx) {
    __shared__ __align__(16) char smem[35840];
    u16*   Ks    = (u16*)smem;                 // [2][4096] K tiles (swizzled)
    u16*   Vs    = (u16*)(smem + 16384);       // [2][4096] V tiles (swizzled)
    float* RedA  = (float*)smem;               // aliases Ks/Vs: post-loop only
    float* RedB  = (float*)(smem + 17408);
    float* lpbuf = (float*)(smem + 34816);

    const int flat = blockIdx.x;          // 0..1023
    const int g    = flat & 31;           // (b*16+h); XCD = g%8 (32 % 8 == 0)
    const int qt   = 31 - (flat >> 5);    // longest blocks first
    const int h = g & 15, b = g >> 4;

    const int tid = threadIdx.x, lane = tid & 63, wv = tid >> 6;
    const int l15 = lane & 15, quad = lane >> 4;

    const size_t headOff = ((size_t)b * N_HEADS + h) * S_LEN * HEAD_DIM;
    const u16* Qh = Q + headOff;
    const u16* Kh = K + headOff;
    const u16* Vh = Vt + headOff;         // d-major: [64][2048]
    u16* Cb = Ctx + (size_t)b * S_LEN * D_MODEL + (size_t)h * HEAD_DIM;

    const int srow = lane >> 3;           // staging: row within 8-row chunk
    const int gch  = (lane & 7) ^ srow;   // swizzled source chunk
    const int swz  = l15 & 7;             // read-side swizzle (row&7 == l15&7)

    const int qBase = qt * 64;

    bf16x8 qb[4][2];
#pragma unroll
    for (int qg = 0; qg < 4; ++qg)
#pragma unroll
        for (int ks = 0; ks < 2; ++ks)
            qb[qg][ks] = *(const bf16x8*)(Qh + (size_t)(qBase + qg * 16 + l15) * 64
                                          + ks * 32 + quad * 8);

    floatx4 o[4][4];                      // O_partial[qg][dg], lane: q=quad*4+r, d=l15
#pragma unroll
    for (int qg = 0; qg < 4; ++qg)
#pragma unroll
        for (int dg = 0; dg < 4; ++dg) o[qg][dg] = (floatx4)(0.0f);
    float lp[4] = {0.0f, 0.0f, 0.0f, 0.0f};

    // prologue: stage tile 0 into buffer 0
#pragma unroll
    for (int t = 0; t < 2; ++t) {
        const int ci = wv * 2 + t;
        gload_lds16(Kh + (size_t)(ci * 8 + srow) * 64 + gch * 8, &Ks[ci * 512]);
        gload_lds16(Vh + (size_t)(ci * 8 + srow) * S_LEN + gch * 8, &Vs[ci * 512]);
    }
    __syncthreads();                      // implicit vmcnt(0): buf0 ready

    for (int kt = 0; kt <= qt; ++kt) {
        const int cur = (kt & 1) * 4096;
        const int nxt = 4096 - cur;

        if (kt < qt) {                    // stage next tile FIRST
            const int kB2 = (kt + 1) * 64;
#pragma unroll
            for (int t = 0; t < 2; ++t) {
                const int ci = wv * 2 + t;
                gload_lds16(Kh + (size_t)(kB2 + ci * 8 + srow) * 64 + gch * 8,
                            &Ks[nxt + ci * 512]);
                gload_lds16(Vh + (size_t)(ci * 8 + srow) * S_LEN + kB2 + gch * 8,
                            &Vs[nxt + ci * 512]);
            }
        }

        bf16x8 ka[2];
#pragma unroll
        for (int ks = 0; ks < 2; ++ks)
            ka[ks] = *(const bf16x8*)&Ks[cur + (wv * 16 + l15) * 64 + ((ks * 4 + quad) ^ swz) * 8];

        bf16x4 vb[4];
#pragma unroll
        for (int dg = 0; dg < 4; ++dg)
            vb[dg] = *(const bf16x4*)&Vs[cur + (dg * 16 + l15) * 64
                                         + (((wv * 2 + (quad >> 1)) ^ swz) * 8) + (quad & 1) * 4];

        __builtin_amdgcn_s_setprio(1);
        floatx4 s[4];
#pragma unroll
        for (int qg = 0; qg < 4; ++qg) {
            s[qg] = (floatx4)(0.0f);
#pragma unroll
            for (int ks = 0; ks < 2; ++ks)
                s[qg] = __builtin_amdgcn_mfma_f32_16x16x32_bf16(ka[ks], qb[qg][ks], s[qg], 0, 0, 0);
        }

        const bool diag = (kt == qt);
#pragma unroll
        for (int qg = 0; qg < 4; ++qg) {
            if (diag && qg < wv) continue;          // fully masked (wave-uniform)
            float p[4];
#pragma unroll
            for (int r = 0; r < 4; ++r) {
                float pv = __builtin_amdgcn_exp2f(s[qg][r]);
                if (diag && qg == wv && (quad * 4 + r > l15)) pv = 0.0f;
                p[r] = pv;
                lp[qg] += pv;
            }
            union { uint2 u; bf16x4 v; } pk;
            pk.u.x = __builtin_amdgcn_perm(__float_as_uint(p[1]), __float_as_uint(p[0]), 0x07060302);
            pk.u.y = __builtin_amdgcn_perm(__float_as_uint(p[3]), __float_as_uint(p[2]), 0x07060302);
#pragma unroll
            for (int dg = 0; dg < 4; ++dg)
                o[qg][dg] = __builtin_amdgcn_mfma_f32_16x16x16bf16_1k(pk.v, vb[dg], o[qg][dg], 0, 0, 0);
        }
        __builtin_amdgcn_s_setprio(0);

        __syncthreads();   // ONE barrier/tile: drains stage + readers done
    }

#pragma unroll
    for (int qg = 0; qg < 4; ++qg) {
        lp[qg] += __shfl_xor(lp[qg], 16);
        lp[qg] += __shfl_xor(lp[qg], 32);
    }
    lpbuf[wv * 64 + quad * 16 + l15] = lp[quad];

    if (wv == 1 || wv == 3) {
        float* R = (wv == 1) ? RedA : RedB;
#pragma unroll
        for (int qg = 0; qg < 4; ++qg)
#pragma unroll
            for (int dg = 0; dg < 4; ++dg)
                *(floatx4*)&R[(dg * 16 + l15) * 68 + qg * 16 + quad * 4] = o[qg][dg];
    }
    __syncthreads();
    if (wv == 0 || wv == 2) {
        const float* R = (wv == 0) ? RedA : RedB;
#pragma unroll
        for (int qg = 0; qg < 4; ++qg)
#pragma unroll
            for (int dg = 0; dg < 4; ++dg)
                o[qg][dg] += *(const floatx4*)&R[(dg * 16 + l15) * 68 + qg * 16 + quad * 4];
    }
    __syncthreads();
    if (wv == 2) {
#pragma unroll
        for (int qg = 0; qg < 4; ++qg)
#pragma unroll
            for (int dg = 0; dg < 4; ++dg)
                *(floatx4*)&RedA[(dg * 16 + l15) * 68 + qg * 16 + quad * 4] = o[qg][dg];
    }
    __syncthreads();
    if (wv == 0) {
#pragma unroll
        for (int qg = 0; qg < 4; ++qg) {
#pragma unroll
            for (int dg = 0; dg < 4; ++dg)
                o[qg][dg] += *(const floatx4*)&RedA[(dg * 16 + l15) * 68 + qg * 16 + quad * 4];
            floatx4 lt = *(const floatx4*)&lpbuf[0 * 64 + qg * 16 + quad * 4];
            lt += *(const floatx4*)&lpbuf[1 * 64 + qg * 16 + quad * 4];
            lt += *(const floatx4*)&lpbuf[2 * 64 + qg * 16 + quad * 4];
            lt += *(const floatx4*)&lpbuf[3 * 64 + qg * 16 + quad * 4];
#pragma unroll
            for (int r = 0; r < 4; ++r) {
                const float inv = 1.0f / lt[r];
                const int row = qBase + qg * 16 + quad * 4 + r;
#pragma unroll
                for (int dg = 0; dg < 4; ++dg)
                    Cb[(size_t)row * D_MODEL + dg * 16 + l15] = f2bf(o[qg][dg][r] * inv);
            }
        }
    }
}

// ---------------------------------------------------------------------------
extern "C" void kernel_launch(void* const* d_in, const int* in_sizes, int n_in,
                              void* d_out, int out_size, void* d_ws, size_t ws_size,
                              hipStream_t stream) {
    const float* hs = (const float*)d_in[0];
    const float* Wq = (const float*)d_in[1];
    const float* Wk = (const float*)d_in[2];
    const float* Wv = (const float*)d_in[3];
    const float* Wo = (const float*)d_in[4];
    const float* bo = (const float*)d_in[5];
    float* out = (float*)d_out;

    const size_t NHS = (size_t)2 * S_LEN * D_MODEL;  // 4M elements
    const size_t NW  = (size_t)D_MODEL * D_MODEL;    // 1M elements

    u16* hsb = (u16*)d_ws;        // 4M
    u16* Wb  = hsb + NHS;         // 4 x 1M (Wq,Wk,Wv,Wo) — contiguous with hsb
    u16* Qb  = Wb + 4 * NW;       // 4M
    u16* Kb  = Qb + NHS;          // 4M
    u16* Vfb = Kb + NHS;          // 4M (standard projection layout)
    u16* Vtb = Vfb + NHS;         // 4M (per-head transposed [d][s])
    u16* Cxb = Vtb + NHS;         // 4M

    cast_all<<<4096, 256, 0, stream>>>(hs, Wq, Wk, Wv, Wo, hsb);

    gemm_qkv<<<768, 256, 0, stream>>>(hsb, Wb, Wb + NW, Wb + 2 * NW,
                                      Qb, Kb, Vfb);

    vtrans<<<dim3(16, 32), 256, 0, stream>>>(Vfb, Vtb);

    attn6<<<1024, 256, 0, stream>>>(Qb, Kb, Vtb, Cxb);

    gemm_out<<<dim3(8, 64), 256, 0, stream>>>(Cxb, Wb + 3 * NW, bo, out);
}